// Round 7
// baseline (520.399 us; speedup 1.0000x reference)
//
#include <hip/hip_runtime.h>
#include <stdint.h>

#define LN_EPS 1e-5f

// LayerNorm(C) + ReLU over a register array. Fully unrolled (reg arrays need
// compile-time indices).
template <int C>
__device__ __forceinline__ void ln_relu(float (&a)[C], const float* __restrict__ g,
                                        const float* __restrict__ b, float inv_c) {
  float p0 = 0.f, p1 = 0.f, p2 = 0.f, p3 = 0.f;
#pragma unroll
  for (int j = 0; j < C; j += 4) { p0 += a[j]; p1 += a[j + 1]; p2 += a[j + 2]; p3 += a[j + 3]; }
  float mu = ((p0 + p1) + (p2 + p3)) * inv_c;
  float q0 = 0.f, q1 = 0.f, q2 = 0.f, q3 = 0.f;
#pragma unroll
  for (int j = 0; j < C; j += 4) {
    float d0 = a[j] - mu, d1 = a[j + 1] - mu, d2 = a[j + 2] - mu, d3 = a[j + 3] - mu;
    a[j] = d0; a[j + 1] = d1; a[j + 2] = d2; a[j + 3] = d3;
    q0 = fmaf(d0, d0, q0); q1 = fmaf(d1, d1, q1); q2 = fmaf(d2, d2, q2); q3 = fmaf(d3, d3, q3);
  }
  float var = ((q0 + q1) + (q2 + q3)) * inv_c;
  float rs = rsqrtf(var + LN_EPS);
#pragma unroll
  for (int j = 0; j < C; ++j) {
    float t = a[j] * rs;
    t = fmaf(t, g[j], b[j]);
    a[j] = fmaxf(t, 0.f);
  }
}

// R7: R5 structure (no prefetch) + __launch_bounds__(256,4) to pin VGPR<=64.
// R6 post-mortem (measured): dist-1 x-prefetch bought only ~12us (169->157us
// kernel) => x-load latency was NOT the dominant exposure. Kernel still ~3.3x
// the 46us VALU-issue floor => stall-cover problem. Remaining suspects:
// occupancy (VGPR>64 => 4 waves/SIMD; <=64 => 8, per waves-halve-at-64) and
// s_load weight-latency chains (which more waves also cover).
// R3 measured that __launch_bounds__(256,4) forces VGPR=64 exactly. R3's
// catastrophe was demand ~110 >> 64 (spill). R5's 1-row live set is ~56-60
// (acc 32 + one 4xfloat4 chunk 16 + temps) — fits under the cap, so the same
// flag now buys 8 waves/SIMD with zero spill. Prefetch dropped (+16 regs
// would blow the cap; it was worth only 7%).
// Watch: WRITE_SIZE must stay 16.02MB (no spill). If bench unchanged, the
// occupancy theory is falsified -> pivot to packed-FMA / lane-split.
__global__ __launch_bounds__(256, 4) void dec_kernel(
    const float* __restrict__ x,
    const float* __restrict__ w1, const float* __restrict__ g1, const float* __restrict__ b1,
    const float* __restrict__ w2, const float* __restrict__ g2, const float* __restrict__ b2,
    const float* __restrict__ w3, const float* __restrict__ b3,
    float* __restrict__ out, int N, int HW)
{
  const int row = blockIdx.x * 256 + threadIdx.x;
  if (row >= N) return;

  const float4* __restrict__ xp = (const float4*)(x + (size_t)row * 64);

  // ---- layer 1: K=64 -> 32, rolled over 4 chunks of 16 ----
  float acc[32];
#pragma unroll
  for (int j = 0; j < 32; ++j) acc[j] = 0.f;

#pragma unroll 1
  for (int c = 0; c < 4; ++c) {
    const float4 x0 = xp[c * 4 + 0];
    const float4 x1 = xp[c * 4 + 1];
    const float4 x2 = xp[c * 4 + 2];
    const float4 x3 = xp[c * 4 + 3];
    const float* __restrict__ wbase = w1 + c * 16 * 32;
#pragma unroll
    for (int q = 0; q < 4; ++q) {
      const float4 xq = (q == 0) ? x0 : (q == 1) ? x1 : (q == 2) ? x2 : x3;
#pragma unroll
      for (int kk = 0; kk < 4; ++kk) {
        const float xk = (kk == 0) ? xq.x : (kk == 1) ? xq.y : (kk == 2) ? xq.z : xq.w;
        const float* __restrict__ wrow = wbase + (q * 4 + kk) * 32;  // uniform -> s_load
#pragma unroll
        for (int j = 0; j < 32; ++j) acc[j] = fmaf(xk, wrow[j], acc[j]);
      }
    }
  }

  ln_relu<32>(acc, g1, b1, 0.03125f);

  // ---- layer 2: K=32 -> 16 (acc[k] needs compile-time k -> full unroll) ----
  float a2[16];
#pragma unroll
  for (int j = 0; j < 16; ++j) a2[j] = 0.f;
#pragma unroll
  for (int k = 0; k < 32; ++k) {
    const float hk = acc[k];
    const float* __restrict__ wrow = w2 + k * 16;        // uniform -> s_load
#pragma unroll
    for (int j = 0; j < 16; ++j) a2[j] = fmaf(hk, wrow[j], a2[j]);
  }

  ln_relu<16>(a2, g2, b2, 0.0625f);

  // ---- layer 3 + channel L2-normalize ----
  float o0 = b3[0], o1 = b3[1], o2 = b3[2];
#pragma unroll
  for (int k = 0; k < 16; ++k) {
    const float hk = a2[k];
    o0 = fmaf(hk, w3[k * 3 + 0], o0);
    o1 = fmaf(hk, w3[k * 3 + 1], o1);
    o2 = fmaf(hk, w3[k * 3 + 2], o2);
  }
  const float nsq = fmaf(o0, o0, fmaf(o1, o1, o2 * o2));
  const float inv = rsqrtf(fmaxf(nsq, 1e-24f));  // == 1/max(||o||,1e-12)
  o0 *= inv; o1 *= inv; o2 *= inv;

  // out[b][c][h][w]; flat = b*3*HW + c*HW + p; lanes consecutive in p -> coalesced
  const unsigned b = (unsigned)row / (unsigned)HW;
  const unsigned p = (unsigned)row - b * (unsigned)HW;
  const size_t obase = (size_t)b * 3 * HW + p;
  out[obase]          = o0;
  out[obase + HW]     = o1;
  out[obase + 2 * HW] = o2;
}

extern "C" void kernel_launch(void* const* d_in, const int* in_sizes, int n_in,
                              void* d_out, int out_size, void* d_ws, size_t ws_size,
                              hipStream_t stream) {
  const float* x  = (const float*)d_in[0];
  const float* w1 = (const float*)d_in[1];
  const float* g1 = (const float*)d_in[2];
  const float* b1 = (const float*)d_in[3];
  const float* w2 = (const float*)d_in[4];
  const float* g2 = (const float*)d_in[5];
  const float* b2 = (const float*)d_in[6];
  const float* w3 = (const float*)d_in[7];
  const float* b3 = (const float*)d_in[8];
  float* out = (float*)d_out;

  const int N  = in_sizes[0] / 64;  // rows
  const int HW = N / 4;             // B = 4 per reference setup
  const int nblocks = (N + 255) / 256;
  dec_kernel<<<nblocks, 256, 0, stream>>>(x, w1, g1, b1, w2, g2, b2, w3, b3, out, N, HW);
}